// Round 7
// baseline (473.191 us; speedup 1.0000x reference)
//
#include <hip/hip_runtime.h>
#include <math.h>

// ---------------------------------------------------------------------------
// 2-layer GAT (H=2 heads, mean over heads), fp32.
// CSR by dst (self-loops at slot 0). Per layer:
//   gemm64_dots: 64x128-tile GEMM with fused attention-dot epilogue
//   agg_fused:   block-per-node (4 waves), inline softmax + gather-aggregate
// ---------------------------------------------------------------------------

#define IN_DIM 128
#define FLATC 128   // HEADS*64

__device__ __forceinline__ float lrelu02(float t) {
    return t > 0.f ? t : 0.2f * t;
}

// ---- CSR build ------------------------------------------------------------

__global__ void count_kernel(const int* __restrict__ dst, int* __restrict__ cnt, int e) {
    int i = blockIdx.x * blockDim.x + threadIdx.x;
    if (i < e) atomicAdd(&cnt[dst[i]], 1);
}

// hierarchical exclusive scan over (cnt+1) -> row_start; self edge at slot 0
__global__ __launch_bounds__(256) void scan_bsum(const int* __restrict__ cnt,
                                                 int* __restrict__ bsum, int n) {
    __shared__ int red[256];
    int t = threadIdx.x;
    int i = blockIdx.x * 256 + t;
    red[t] = (i < n) ? cnt[i] + 1 : 0;
    __syncthreads();
#pragma unroll
    for (int off = 128; off > 0; off >>= 1) {
        if (t < off) red[t] += red[t + off];
        __syncthreads();
    }
    if (t == 0) bsum[blockIdx.x] = red[0];
}

__global__ __launch_bounds__(1024) void scan_boff(const int* __restrict__ bsum,
                                                  int* __restrict__ boff,
                                                  int* __restrict__ row_start,
                                                  int nb, int n) {
    __shared__ int s[1024];
    int t = threadIdx.x;
    int v = (t < nb) ? bsum[t] : 0;
    s[t] = v;
    __syncthreads();
    for (int off = 1; off < 1024; off <<= 1) {
        int u = (t >= off) ? s[t - off] : 0;
        __syncthreads();
        s[t] += u;
        __syncthreads();
    }
    if (t < nb) boff[t] = s[t] - v;
    if (t == nb - 1) row_start[n] = s[t];   // total = E + N
}

__global__ __launch_bounds__(256) void scan_write(const int* __restrict__ cnt,
                                                  const int* __restrict__ boff,
                                                  int* __restrict__ row_start,
                                                  int* __restrict__ cursor,
                                                  int* __restrict__ adj, int n) {
    __shared__ int s[256];
    int t = threadIdx.x;
    int i = blockIdx.x * 256 + t;
    int v = (i < n) ? cnt[i] + 1 : 0;
    s[t] = v;
    __syncthreads();
    for (int off = 1; off < 256; off <<= 1) {
        int u = (t >= off) ? s[t - off] : 0;
        __syncthreads();
        s[t] += u;
        __syncthreads();
    }
    if (i < n) {
        int rs = boff[blockIdx.x] + s[t] - v;
        row_start[i] = rs;
        adj[rs] = i;          // self edge at slot 0
        cursor[i] = rs + 1;
    }
}

__global__ void scatter_kernel(const int* __restrict__ src, const int* __restrict__ dst,
                               int* __restrict__ cursor, int* __restrict__ adj, int e) {
    int i = blockIdx.x * blockDim.x + threadIdx.x;
    if (i < e) {
        int d = dst[i];
        int pos = atomicAdd(&cursor[d], 1);
        adj[pos] = src[i];
    }
}

// ---- GEMM 64x128 tile + fused attention dots ------------------------------
// C[n,128] = A[n,K] @ B[K,128]; es2/ed2[row] = per-head <C_row, att>.
// thread (tx,ty): rows ty*4+r (r<4), cols tx+16*c (c<8). head0=c<4, head1=c>=4.

__global__ __launch_bounds__(256) void gemm64_dots(const float* __restrict__ A,
                                                   const float* __restrict__ B,
                                                   float* __restrict__ C,
                                                   const float* __restrict__ att_s,
                                                   const float* __restrict__ att_d,
                                                   float2* __restrict__ es2,
                                                   float2* __restrict__ ed2,
                                                   int nrows, int K) {
    __shared__ float As[64][33];
    __shared__ float Bs[32][128];
    const int tid = threadIdx.x;
    const int tx = tid & 15;
    const int ty = tid >> 4;
    const int row0 = blockIdx.x * 64;

    float acc[4][8];
#pragma unroll
    for (int r = 0; r < 4; ++r)
#pragma unroll
        for (int c = 0; c < 8; ++c) acc[r][c] = 0.f;

    for (int k0 = 0; k0 < K; k0 += 32) {
        // A tile 64x32: 2 float4 per thread
#pragma unroll
        for (int i = 0; i < 2; ++i) {
            int idx = tid + i * 256;
            int r = idx >> 3;
            int c4 = (idx & 7) * 4;
            float4 v = make_float4(0.f, 0.f, 0.f, 0.f);
            int row = row0 + r;
            if (row < nrows) v = *(const float4*)(A + (size_t)row * K + k0 + c4);
            As[r][c4 + 0] = v.x; As[r][c4 + 1] = v.y;
            As[r][c4 + 2] = v.z; As[r][c4 + 3] = v.w;
        }
        // B tile 32x128: 4 float4 per thread
#pragma unroll
        for (int i = 0; i < 4; ++i) {
            int idx = tid + i * 256;
            int r = idx >> 5;
            int c4 = (idx & 31) * 4;
            float4 v = *(const float4*)(B + (size_t)(k0 + r) * FLATC + c4);
            *(float4*)&Bs[r][c4] = v;
        }
        __syncthreads();
#pragma unroll
        for (int kk = 0; kk < 32; ++kk) {
            float a[4], b[8];
#pragma unroll
            for (int r = 0; r < 4; ++r) a[r] = As[ty * 4 + r][kk];
#pragma unroll
            for (int c = 0; c < 8; ++c) b[c] = Bs[kk][tx + 16 * c];
#pragma unroll
            for (int r = 0; r < 4; ++r)
#pragma unroll
                for (int c = 0; c < 8; ++c) acc[r][c] = fmaf(a[r], b[c], acc[r][c]);
        }
        __syncthreads();
    }

    // epilogue: C write + attention dots (16-lane shuffle reduce over tx)
    float asr[8], adr[8];
#pragma unroll
    for (int c = 0; c < 8; ++c) {
        asr[c] = att_s[tx + 16 * c];
        adr[c] = att_d[tx + 16 * c];
    }
#pragma unroll
    for (int r = 0; r < 4; ++r) {
        int row = row0 + ty * 4 + r;
        float s0 = 0.f, s1 = 0.f, d0 = 0.f, d1 = 0.f;
#pragma unroll
        for (int c = 0; c < 4; ++c) {
            s0 = fmaf(acc[r][c], asr[c], s0);
            d0 = fmaf(acc[r][c], adr[c], d0);
        }
#pragma unroll
        for (int c = 4; c < 8; ++c) {
            s1 = fmaf(acc[r][c], asr[c], s1);
            d1 = fmaf(acc[r][c], adr[c], d1);
        }
#pragma unroll
        for (int m = 1; m < 16; m <<= 1) {
            s0 += __shfl_xor(s0, m);
            s1 += __shfl_xor(s1, m);
            d0 += __shfl_xor(d0, m);
            d1 += __shfl_xor(d1, m);
        }
        if (row < nrows) {
#pragma unroll
            for (int c = 0; c < 8; ++c) C[(size_t)row * FLATC + tx + 16 * c] = acc[r][c];
            if (tx == 0) {
                es2[row] = make_float2(s0, s1);
                ed2[row] = make_float2(d0, d1);
            }
        }
    }
}

// ---- fused softmax + aggregate: one block (4 waves) per destination node --
// Each wave computes softmax stats (redundant, es2 is L2-resident), then
// aggregates its quarter of the edges; LDS reduce; bias(+relu); write.

__global__ __launch_bounds__(256) void agg_fused(const int* __restrict__ row_start,
                                                 const int* __restrict__ adj,
                                                 const float* __restrict__ h,
                                                 const float2* __restrict__ es2,
                                                 const float2* __restrict__ ed2,
                                                 const float* __restrict__ bias,
                                                 float* __restrict__ out,
                                                 int n, int do_relu) {
    __shared__ float red[3][128];
    const int node = blockIdx.x;
    const int tid = threadIdx.x;
    const int wid = tid >> 6;
    const int lane = tid & 63;
    const int head = lane >> 5;
    const int beg = row_start[node];
    const int end = row_start[node + 1];
    const int deg = end - beg;
    const float2 edv = ed2[node];

    // softmax stats over the row (each wave computes them; deg>=1 always)
    float m0 = -3.0e38f, m1 = -3.0e38f;
    float f0 = 0.f, f1 = 0.f;   // first-strip per-lane values
    for (int j = beg + lane; j < end; j += 64) {
        float2 ev = es2[adj[j]];
        float g0 = lrelu02(ev.x + edv.x);
        float g1 = lrelu02(ev.y + edv.y);
        if (j < beg + 64) { f0 = g0; f1 = g1; }
        m0 = fmaxf(m0, g0);
        m1 = fmaxf(m1, g1);
    }
#pragma unroll
    for (int off = 1; off < 64; off <<= 1) {
        m0 = fmaxf(m0, __shfl_xor(m0, off));
        m1 = fmaxf(m1, __shfl_xor(m1, off));
    }
    float s0 = 0.f, s1 = 0.f;
    if (deg <= 64) {
        if (lane < deg) { s0 = expf(f0 - m0); s1 = expf(f1 - m1); }
    } else {
        for (int j = beg + lane; j < end; j += 64) {
            float2 ev = es2[adj[j]];
            s0 += expf(lrelu02(ev.x + edv.x) - m0);
            s1 += expf(lrelu02(ev.y + edv.y) - m1);
        }
    }
#pragma unroll
    for (int off = 1; off < 64; off <<= 1) {
        s0 += __shfl_xor(s0, off);
        s1 += __shfl_xor(s1, off);
    }
    const float mh   = head ? m1 : m0;
    const float edh  = head ? edv.y : edv.x;
    const float invh = 1.f / ((head ? s1 : s0) + 1e-16f);

    // aggregate this wave's quarter of the edges (stride 4, 2-deep unroll)
    const float* hp = h + 2 * lane;
    float ax = 0.f, ay = 0.f;
    int j = beg + wid;
    for (; j + 4 < end; j += 8) {
        int i0 = adj[j];
        int i1 = adj[j + 4];
        float2 e0 = es2[i0];
        float2 e1 = es2[i1];
        float2 v0 = *(const float2*)(hp + (size_t)i0 * FLATC);
        float2 v1 = *(const float2*)(hp + (size_t)i1 * FLATC);
        float a0 = expf(lrelu02((head ? e0.y : e0.x) + edh) - mh) * invh;
        float a1 = expf(lrelu02((head ? e1.y : e1.x) + edh) - mh) * invh;
        ax = fmaf(a0, v0.x, ax); ay = fmaf(a0, v0.y, ay);
        ax = fmaf(a1, v1.x, ax); ay = fmaf(a1, v1.y, ay);
    }
    if (j < end) {
        int i0 = adj[j];
        float2 e0 = es2[i0];
        float2 v0 = *(const float2*)(hp + (size_t)i0 * FLATC);
        float a0 = expf(lrelu02((head ? e0.y : e0.x) + edh) - mh) * invh;
        ax = fmaf(a0, v0.x, ax); ay = fmaf(a0, v0.y, ay);
    }

    // cross-wave reduce
    if (wid) {
        red[wid - 1][2 * lane]     = ax;
        red[wid - 1][2 * lane + 1] = ay;
    }
    __syncthreads();
    if (wid == 0) {
        ax += red[0][2 * lane] + red[1][2 * lane] + red[2][2 * lane];
        ay += red[0][2 * lane + 1] + red[1][2 * lane + 1] + red[2][2 * lane + 1];
        float ox = 0.5f * (ax + __shfl_xor(ax, 32));
        float oy = 0.5f * (ay + __shfl_xor(ay, 32));
        if (lane < 32) {
            int c = 2 * lane;
            ox += bias[c];
            oy += bias[c + 1];
            if (do_relu) { ox = fmaxf(ox, 0.f); oy = fmaxf(oy, 0.f); }
            *(float2*)(out + (size_t)node * 64 + c) = make_float2(ox, oy);
        }
    }
}

// ---------------------------------------------------------------------------

extern "C" void kernel_launch(void* const* d_in, const int* in_sizes, int n_in,
                              void* d_out, int out_size, void* d_ws, size_t ws_size,
                              hipStream_t stream) {
    const float* x   = (const float*)d_in[0];
    const int*   ei  = (const int*)d_in[1];
    const float* W1  = (const float*)d_in[2];
    const float* as1 = (const float*)d_in[3];
    const float* ad1 = (const float*)d_in[4];
    const float* b1  = (const float*)d_in[5];
    const float* W2  = (const float*)d_in[6];
    const float* as2 = (const float*)d_in[7];
    const float* ad2 = (const float*)d_in[8];
    const float* b2  = (const float*)d_in[9];

    const int N_ = in_sizes[0] / IN_DIM;   // 50000
    const int E_ = in_sizes[1] / 2;        // 800000
    const int* src = ei;
    const int* dst = ei + E_;
    const int TOT = E_ + N_;               // CSR slots incl self loops

    auto align16 = [](size_t v) { return (v + 15) & ~(size_t)15; };
    char* p = (char*)d_ws;
    int* cnt       = (int*)p; p += align16((size_t)N_ * 4);
    int* row_start = (int*)p; p += align16((size_t)(N_ + 1) * 4);
    int* cursor    = (int*)p; p += align16((size_t)N_ * 4);
    int* adj       = (int*)p; p += align16((size_t)TOT * 4);
    int* bsum      = (int*)p; p += align16((size_t)1024 * 4);
    int* boff      = (int*)p; p += align16((size_t)1024 * 4);
    float* h       = (float*)p; p += align16((size_t)N_ * FLATC * 4);
    float* out1    = (float*)p; p += align16((size_t)N_ * 64 * 4);
    float* es      = (float*)p; p += align16((size_t)N_ * 2 * 4);
    float* ed      = (float*)p; p += align16((size_t)N_ * 2 * 4);
    (void)ws_size; (void)n_in; (void)out_size;

    const int NB = (N_ + 255) / 256;

    // --- CSR build (self-loops at slot 0, +1 folded into scan) ---
    hipMemsetAsync(cnt, 0, (size_t)N_ * 4, stream);
    count_kernel<<<(E_ + 255) / 256, 256, 0, stream>>>(dst, cnt, E_);
    scan_bsum<<<NB, 256, 0, stream>>>(cnt, bsum, N_);
    scan_boff<<<1, 1024, 0, stream>>>(bsum, boff, row_start, NB, N_);
    scan_write<<<NB, 256, 0, stream>>>(cnt, boff, row_start, cursor, adj, N_);
    scatter_kernel<<<(E_ + 255) / 256, 256, 0, stream>>>(src, dst, cursor, adj, E_);

    const int gG = (N_ + 63) / 64;

    // --- layer 1 ---
    gemm64_dots<<<gG, 256, 0, stream>>>(x, W1, h, as1, ad1,
                                        (float2*)es, (float2*)ed, N_, IN_DIM);
    agg_fused<<<N_, 256, 0, stream>>>(row_start, adj, h, (const float2*)es,
                                      (const float2*)ed, b1, out1, N_, 1);

    // --- layer 2 ---
    gemm64_dots<<<gG, 256, 0, stream>>>(out1, W2, h, as2, ad2,
                                        (float2*)es, (float2*)ed, N_, 64);
    agg_fused<<<N_, 256, 0, stream>>>(row_start, adj, h, (const float2*)es,
                                      (const float2*)ed, b2, (float*)d_out, N_, 0);
}

// Round 8
// 368.307 us; speedup vs baseline: 1.2848x; 1.2848x over previous
//
#include <hip/hip_runtime.h>
#include <hip/hip_fp16.h>
#include <math.h>

// ---------------------------------------------------------------------------
// 2-layer GAT (H=2 heads, mean over heads), fp32 compute, fp16 gather payload.
// CSR by dst (self-loops at slot 0). Per layer:
//   gemm64_dots:   64x128-tile GEMM, fused attention-dot epilogue, writes h16
//   softmax_alpha: wave-per-node, single-exp fast path (deg<=64)
//   agg:           wave-per-node, 4-deep unrolled fp16 gather + fp32 FMA
// ---------------------------------------------------------------------------

#define IN_DIM 128
#define FLATC 128   // HEADS*64

__device__ __forceinline__ float lrelu02(float t) {
    return t > 0.f ? t : 0.2f * t;
}

// ---- CSR build ------------------------------------------------------------

__global__ void count_kernel(const int* __restrict__ dst, int* __restrict__ cnt, int e) {
    int i = blockIdx.x * blockDim.x + threadIdx.x;
    if (i < e) atomicAdd(&cnt[dst[i]], 1);
}

// hierarchical exclusive scan over (cnt+1) -> row_start; self edge at slot 0
__global__ __launch_bounds__(256) void scan_bsum(const int* __restrict__ cnt,
                                                 int* __restrict__ bsum, int n) {
    __shared__ int red[256];
    int t = threadIdx.x;
    int i = blockIdx.x * 256 + t;
    red[t] = (i < n) ? cnt[i] + 1 : 0;
    __syncthreads();
#pragma unroll
    for (int off = 128; off > 0; off >>= 1) {
        if (t < off) red[t] += red[t + off];
        __syncthreads();
    }
    if (t == 0) bsum[blockIdx.x] = red[0];
}

__global__ __launch_bounds__(1024) void scan_boff(const int* __restrict__ bsum,
                                                  int* __restrict__ boff,
                                                  int* __restrict__ row_start,
                                                  int nb, int n) {
    __shared__ int s[1024];
    int t = threadIdx.x;
    int v = (t < nb) ? bsum[t] : 0;
    s[t] = v;
    __syncthreads();
    for (int off = 1; off < 1024; off <<= 1) {
        int u = (t >= off) ? s[t - off] : 0;
        __syncthreads();
        s[t] += u;
        __syncthreads();
    }
    if (t < nb) boff[t] = s[t] - v;
    if (t == nb - 1) row_start[n] = s[t];   // total = E + N
}

__global__ __launch_bounds__(256) void scan_write(const int* __restrict__ cnt,
                                                  const int* __restrict__ boff,
                                                  int* __restrict__ row_start,
                                                  int* __restrict__ cursor,
                                                  int* __restrict__ adj, int n) {
    __shared__ int s[256];
    int t = threadIdx.x;
    int i = blockIdx.x * 256 + t;
    int v = (i < n) ? cnt[i] + 1 : 0;
    s[t] = v;
    __syncthreads();
    for (int off = 1; off < 256; off <<= 1) {
        int u = (t >= off) ? s[t - off] : 0;
        __syncthreads();
        s[t] += u;
        __syncthreads();
    }
    if (i < n) {
        int rs = boff[blockIdx.x] + s[t] - v;
        row_start[i] = rs;
        adj[rs] = i;          // self edge at slot 0
        cursor[i] = rs + 1;
    }
}

__global__ void scatter_kernel(const int* __restrict__ src, const int* __restrict__ dst,
                               int* __restrict__ cursor, int* __restrict__ adj, int e) {
    int i = blockIdx.x * blockDim.x + threadIdx.x;
    if (i < e) {
        int d = dst[i];
        int pos = atomicAdd(&cursor[d], 1);
        adj[pos] = src[i];
    }
}

// ---- GEMM 64x128 tile + fused attention dots, fp16 output -----------------
// h16[n,128] = fp16(A[n,K] @ B[K,128]); es2/ed2[row] = per-head <C_row, att>.
// thread (tx,ty): rows ty*4+r (r<4), cols tx+16*c (c<8). head0=c<4, head1=c>=4.

__global__ __launch_bounds__(256) void gemm64_dots(const float* __restrict__ A,
                                                   const float* __restrict__ B,
                                                   __half* __restrict__ h16,
                                                   const float* __restrict__ att_s,
                                                   const float* __restrict__ att_d,
                                                   float2* __restrict__ es2,
                                                   float2* __restrict__ ed2,
                                                   int nrows, int K) {
    __shared__ float As[64][33];
    __shared__ float Bs[32][128];
    const int tid = threadIdx.x;
    const int tx = tid & 15;
    const int ty = tid >> 4;
    const int row0 = blockIdx.x * 64;

    float acc[4][8];
#pragma unroll
    for (int r = 0; r < 4; ++r)
#pragma unroll
        for (int c = 0; c < 8; ++c) acc[r][c] = 0.f;

    for (int k0 = 0; k0 < K; k0 += 32) {
        // A tile 64x32: 2 float4 per thread
#pragma unroll
        for (int i = 0; i < 2; ++i) {
            int idx = tid + i * 256;
            int r = idx >> 3;
            int c4 = (idx & 7) * 4;
            float4 v = make_float4(0.f, 0.f, 0.f, 0.f);
            int row = row0 + r;
            if (row < nrows) v = *(const float4*)(A + (size_t)row * K + k0 + c4);
            As[r][c4 + 0] = v.x; As[r][c4 + 1] = v.y;
            As[r][c4 + 2] = v.z; As[r][c4 + 3] = v.w;
        }
        // B tile 32x128: 4 float4 per thread
#pragma unroll
        for (int i = 0; i < 4; ++i) {
            int idx = tid + i * 256;
            int r = idx >> 5;
            int c4 = (idx & 31) * 4;
            float4 v = *(const float4*)(B + (size_t)(k0 + r) * FLATC + c4);
            *(float4*)&Bs[r][c4] = v;
        }
        __syncthreads();
#pragma unroll
        for (int kk = 0; kk < 32; ++kk) {
            float a[4], b[8];
#pragma unroll
            for (int r = 0; r < 4; ++r) a[r] = As[ty * 4 + r][kk];
#pragma unroll
            for (int c = 0; c < 8; ++c) b[c] = Bs[kk][tx + 16 * c];
#pragma unroll
            for (int r = 0; r < 4; ++r)
#pragma unroll
                for (int c = 0; c < 8; ++c) acc[r][c] = fmaf(a[r], b[c], acc[r][c]);
        }
        __syncthreads();
    }

    // epilogue: h16 write + attention dots (16-lane shuffle reduce over tx)
    float asr[8], adr[8];
#pragma unroll
    for (int c = 0; c < 8; ++c) {
        asr[c] = att_s[tx + 16 * c];
        adr[c] = att_d[tx + 16 * c];
    }
#pragma unroll
    for (int r = 0; r < 4; ++r) {
        int row = row0 + ty * 4 + r;
        float s0 = 0.f, s1 = 0.f, d0 = 0.f, d1 = 0.f;
#pragma unroll
        for (int c = 0; c < 4; ++c) {
            s0 = fmaf(acc[r][c], asr[c], s0);
            d0 = fmaf(acc[r][c], adr[c], d0);
        }
#pragma unroll
        for (int c = 4; c < 8; ++c) {
            s1 = fmaf(acc[r][c], asr[c], s1);
            d1 = fmaf(acc[r][c], adr[c], d1);
        }
#pragma unroll
        for (int m = 1; m < 16; m <<= 1) {
            s0 += __shfl_xor(s0, m);
            s1 += __shfl_xor(s1, m);
            d0 += __shfl_xor(d0, m);
            d1 += __shfl_xor(d1, m);
        }
        if (row < nrows) {
#pragma unroll
            for (int c = 0; c < 8; ++c)
                h16[(size_t)row * FLATC + tx + 16 * c] = __float2half_rn(acc[r][c]);
            if (tx == 0) {
                es2[row] = make_float2(s0, s1);
                ed2[row] = make_float2(d0, d1);
            }
        }
    }
}

// ---- softmax + per-edge alpha (wave per node) -----------------------------
// Fast path (deg<=64): one strip, butterfly max, ONE exp per lane per head.

__global__ __launch_bounds__(256) void softmax_alpha(const int* __restrict__ row_start,
                                                     const int* __restrict__ adj,
                                                     const float2* __restrict__ es2,
                                                     const float2* __restrict__ ed2,
                                                     float2* __restrict__ alpha2,
                                                     int n) {
    int node = blockIdx.x * 4 + (threadIdx.x >> 6);
    if (node >= n) return;
    const int lane = threadIdx.x & 63;
    const int beg = row_start[node];
    const int end = row_start[node + 1];
    const float2 edv = ed2[node];

    if (end - beg <= 64) {
        int j = beg + lane;
        bool act = j < end;
        int id = adj[act ? j : beg];
        float2 ev = es2[id];
        float f0 = lrelu02(ev.x + edv.x);
        float f1 = lrelu02(ev.y + edv.y);
        float m0 = act ? f0 : -3.0e38f;
        float m1 = act ? f1 : -3.0e38f;
#pragma unroll
        for (int off = 1; off < 64; off <<= 1) {
            m0 = fmaxf(m0, __shfl_xor(m0, off));
            m1 = fmaxf(m1, __shfl_xor(m1, off));
        }
        float p0 = act ? expf(f0 - m0) : 0.f;
        float p1 = act ? expf(f1 - m1) : 0.f;
        float s0 = p0, s1 = p1;
#pragma unroll
        for (int off = 1; off < 64; off <<= 1) {
            s0 += __shfl_xor(s0, off);
            s1 += __shfl_xor(s1, off);
        }
        if (act)
            alpha2[j] = make_float2(p0 / (s0 + 1e-16f), p1 / (s1 + 1e-16f));
        return;
    }

    // general path (deg > 64): online softmax across strips
    float m0 = -3.0e38f, m1 = -3.0e38f;
    float s0 = 0.f, s1 = 0.f;
    for (int j = beg + lane; j < end; j += 64) {
        float2 ev = es2[adj[j]];
        float f0 = lrelu02(ev.x + edv.x);
        float f1 = lrelu02(ev.y + edv.y);
        float mn0 = fmaxf(m0, f0);
        s0 = s0 * expf(m0 - mn0) + expf(f0 - mn0);
        m0 = mn0;
        float mn1 = fmaxf(m1, f1);
        s1 = s1 * expf(m1 - mn1) + expf(f1 - mn1);
        m1 = mn1;
    }
#pragma unroll
    for (int off = 1; off < 64; off <<= 1) {
        float mo0 = __shfl_xor(m0, off), so0 = __shfl_xor(s0, off);
        float mo1 = __shfl_xor(m1, off), so1 = __shfl_xor(s1, off);
        float mn0 = fmaxf(m0, mo0);
        s0 = s0 * expf(m0 - mn0) + so0 * expf(mo0 - mn0);
        m0 = mn0;
        float mn1 = fmaxf(m1, mo1);
        s1 = s1 * expf(m1 - mn1) + so1 * expf(mo1 - mn1);
        m1 = mn1;
    }
    const float inv0 = 1.f / (s0 + 1e-16f);
    const float inv1 = 1.f / (s1 + 1e-16f);
    for (int j = beg + lane; j < end; j += 64) {
        float2 ev = es2[adj[j]];
        float f0 = lrelu02(ev.x + edv.x);
        float f1 = lrelu02(ev.y + edv.y);
        alpha2[j] = make_float2(expf(f0 - m0) * inv0, expf(f1 - m1) * inv1);
    }
}

// ---- aggregate: out[n,64] = mean_h(sum_j alpha_j * h16[adj_j]) + bias -----
// wave per node, 4-deep unrolled main loop + scalar remainder (no masking).

__global__ __launch_bounds__(256) void agg(const int* __restrict__ row_start,
                                           const int* __restrict__ adj,
                                           const __half2* __restrict__ h16,
                                           const float2* __restrict__ alpha2,
                                           const float* __restrict__ bias,
                                           float* __restrict__ out,
                                           int n, int do_relu) {
    int node = blockIdx.x * 4 + (threadIdx.x >> 6);
    if (node >= n) return;
    const int lane = threadIdx.x & 63;
    const int head = lane >> 5;
    const int beg = row_start[node];
    const int end = row_start[node + 1];
    const __half2* hp = h16 + lane;      // h16 row = 64 __half2

    float ax = 0.f, ay = 0.f;
    int j = beg;
    for (; j + 4 <= end; j += 4) {
        int i0 = adj[j], i1 = adj[j + 1], i2 = adj[j + 2], i3 = adj[j + 3];
        float2 a0 = alpha2[j], a1 = alpha2[j + 1];
        float2 a2 = alpha2[j + 2], a3 = alpha2[j + 3];
        __half2 v0 = hp[(size_t)i0 * 64];
        __half2 v1 = hp[(size_t)i1 * 64];
        __half2 v2 = hp[(size_t)i2 * 64];
        __half2 v3 = hp[(size_t)i3 * 64];
        float w0 = head ? a0.y : a0.x;
        float w1 = head ? a1.y : a1.x;
        float w2 = head ? a2.y : a2.x;
        float w3 = head ? a3.y : a3.x;
        float2 f0 = __half22float2(v0);
        float2 f1 = __half22float2(v1);
        float2 f2 = __half22float2(v2);
        float2 f3 = __half22float2(v3);
        ax = fmaf(w0, f0.x, ax); ay = fmaf(w0, f0.y, ay);
        ax = fmaf(w1, f1.x, ax); ay = fmaf(w1, f1.y, ay);
        ax = fmaf(w2, f2.x, ax); ay = fmaf(w2, f2.y, ay);
        ax = fmaf(w3, f3.x, ax); ay = fmaf(w3, f3.y, ay);
    }
    for (; j < end; ++j) {
        int i0 = adj[j];
        float2 a0 = alpha2[j];
        float w0 = head ? a0.y : a0.x;
        float2 f0 = __half22float2(hp[(size_t)i0 * 64]);
        ax = fmaf(w0, f0.x, ax); ay = fmaf(w0, f0.y, ay);
    }

    // mean over heads: lane l (head0 ch 2l,2l+1) pairs with lane l+32
    float ox = 0.5f * (ax + __shfl_xor(ax, 32));
    float oy = 0.5f * (ay + __shfl_xor(ay, 32));
    if (lane < 32) {
        int c = 2 * lane;
        ox += bias[c];
        oy += bias[c + 1];
        if (do_relu) { ox = fmaxf(ox, 0.f); oy = fmaxf(oy, 0.f); }
        *(float2*)(out + (size_t)node * 64 + c) = make_float2(ox, oy);
    }
}

// ---------------------------------------------------------------------------

extern "C" void kernel_launch(void* const* d_in, const int* in_sizes, int n_in,
                              void* d_out, int out_size, void* d_ws, size_t ws_size,
                              hipStream_t stream) {
    const float* x   = (const float*)d_in[0];
    const int*   ei  = (const int*)d_in[1];
    const float* W1  = (const float*)d_in[2];
    const float* as1 = (const float*)d_in[3];
    const float* ad1 = (const float*)d_in[4];
    const float* b1  = (const float*)d_in[5];
    const float* W2  = (const float*)d_in[6];
    const float* as2 = (const float*)d_in[7];
    const float* ad2 = (const float*)d_in[8];
    const float* b2  = (const float*)d_in[9];

    const int N_ = in_sizes[0] / IN_DIM;   // 50000
    const int E_ = in_sizes[1] / 2;        // 800000
    const int* src = ei;
    const int* dst = ei + E_;
    const int TOT = E_ + N_;               // CSR slots incl self loops

    auto align16 = [](size_t v) { return (v + 15) & ~(size_t)15; };
    char* p = (char*)d_ws;
    int* cnt       = (int*)p; p += align16((size_t)N_ * 4);
    int* row_start = (int*)p; p += align16((size_t)(N_ + 1) * 4);
    int* cursor    = (int*)p; p += align16((size_t)N_ * 4);
    int* adj       = (int*)p; p += align16((size_t)TOT * 4);
    int* bsum      = (int*)p; p += align16((size_t)1024 * 4);
    int* boff      = (int*)p; p += align16((size_t)1024 * 4);
    __half* h16    = (__half*)p; p += align16((size_t)N_ * FLATC * 2);
    float* out1    = (float*)p; p += align16((size_t)N_ * 64 * 4);
    float* es      = (float*)p; p += align16((size_t)N_ * 2 * 4);
    float* ed      = (float*)p; p += align16((size_t)N_ * 2 * 4);
    float* alpha   = (float*)p; p += align16((size_t)TOT * 2 * 4);
    (void)ws_size; (void)n_in; (void)out_size;

    const int NB = (N_ + 255) / 256;

    // --- CSR build (self-loops at slot 0, +1 folded into scan) ---
    hipMemsetAsync(cnt, 0, (size_t)N_ * 4, stream);
    count_kernel<<<(E_ + 255) / 256, 256, 0, stream>>>(dst, cnt, E_);
    scan_bsum<<<NB, 256, 0, stream>>>(cnt, bsum, N_);
    scan_boff<<<1, 1024, 0, stream>>>(bsum, boff, row_start, NB, N_);
    scan_write<<<NB, 256, 0, stream>>>(cnt, boff, row_start, cursor, adj, N_);
    scatter_kernel<<<(E_ + 255) / 256, 256, 0, stream>>>(src, dst, cursor, adj, E_);

    const int gG = (N_ + 63) / 64;
    const int gN4 = (N_ + 3) / 4;

    // --- layer 1 ---
    gemm64_dots<<<gG, 256, 0, stream>>>(x, W1, h16, as1, ad1,
                                        (float2*)es, (float2*)ed, N_, IN_DIM);
    softmax_alpha<<<gN4, 256, 0, stream>>>(row_start, adj, (const float2*)es,
                                           (const float2*)ed, (float2*)alpha, N_);
    agg<<<gN4, 256, 0, stream>>>(row_start, adj, (const __half2*)h16,
                                 (const float2*)alpha, b1, out1, N_, 1);

    // --- layer 2 ---
    gemm64_dots<<<gG, 256, 0, stream>>>(out1, W2, h16, as2, ad2,
                                        (float2*)es, (float2*)ed, N_, 64);
    softmax_alpha<<<gN4, 256, 0, stream>>>(row_start, adj, (const float2*)es,
                                           (const float2*)ed, (float2*)alpha, N_);
    agg<<<gN4, 256, 0, stream>>>(row_start, adj, (const __half2*)h16,
                                 (const float2*)alpha, b2, (float*)d_out, N_, 0);
}

// Round 15
// 338.693 us; speedup vs baseline: 1.3971x; 1.0874x over previous
//
#include <hip/hip_runtime.h>
#include <hip/hip_fp16.h>
#include <math.h>

// ---------------------------------------------------------------------------
// 2-layer GAT (H=2 heads, mean over heads), fp32 compute, fp16 gather payload.
// CSR by dst (self-loops at slot 0), built with XCD-local bucketed scatter.
// Per layer:
//   gemm64_dots:   64x128 tile, transposed-A LDS (b128 reads), fused dots
//   softmax_alpha: wave-per-node, single-exp fast path (deg<=64)
//   agg:           wave-per-node, 4-deep unrolled fp16 gather + fp32 FMA
// ---------------------------------------------------------------------------

#define IN_DIM 128
#define FLATC 128      // HEADS*64
#define BKT_SHIFT 9    // 512 nodes per bucket

__device__ __forceinline__ float lrelu02(float t) {
    return t > 0.f ? t : 0.2f * t;
}

// ---- CSR build ------------------------------------------------------------

// cnt[d]++ and remember each edge's rank within its destination
__global__ void count_kernel(const int* __restrict__ dst, int* __restrict__ cnt,
                             int* __restrict__ rank, int e) {
    int i = blockIdx.x * blockDim.x + threadIdx.x;
    if (i < e) rank[i] = atomicAdd(&cnt[dst[i]], 1);
}

// hierarchical exclusive scan over (cnt+1) -> row_start; self edge at slot 0
__global__ __launch_bounds__(256) void scan_bsum(const int* __restrict__ cnt,
                                                 int* __restrict__ bsum, int n) {
    __shared__ int red[256];
    int t = threadIdx.x;
    int i = blockIdx.x * 256 + t;
    red[t] = (i < n) ? cnt[i] + 1 : 0;
    __syncthreads();
#pragma unroll
    for (int off = 128; off > 0; off >>= 1) {
        if (t < off) red[t] += red[t + off];
        __syncthreads();
    }
    if (t == 0) bsum[blockIdx.x] = red[0];
}

__global__ __launch_bounds__(1024) void scan_boff(const int* __restrict__ bsum,
                                                  int* __restrict__ boff,
                                                  int* __restrict__ row_start,
                                                  int nb, int n) {
    __shared__ int s[1024];
    int t = threadIdx.x;
    int v = (t < nb) ? bsum[t] : 0;
    s[t] = v;
    __syncthreads();
    for (int off = 1; off < 1024; off <<= 1) {
        int u = (t >= off) ? s[t - off] : 0;
        __syncthreads();
        s[t] += u;
        __syncthreads();
    }
    if (t < nb) boff[t] = s[t] - v;
    if (t == nb - 1) row_start[n] = s[t];   // total = E + N
}

__global__ __launch_bounds__(256) void scan_write(const int* __restrict__ cnt,
                                                  const int* __restrict__ boff,
                                                  int* __restrict__ row_start,
                                                  int* __restrict__ adj, int n) {
    __shared__ int s[256];
    int t = threadIdx.x;
    int i = blockIdx.x * 256 + t;
    int v = (i < n) ? cnt[i] + 1 : 0;
    s[t] = v;
    __syncthreads();
    for (int off = 1; off < 256; off <<= 1) {
        int u = (t >= off) ? s[t - off] : 0;
        __syncthreads();
        s[t] += u;
        __syncthreads();
    }
    if (i < n) {
        int rs = boff[blockIdx.x] + s[t] - v;
        row_start[i] = rs;
        adj[rs] = i;          // self edge at slot 0
    }
}

__global__ void init_gcur(const int* __restrict__ row_start, int* __restrict__ gcur,
                          int nbk, int n) {
    int b = blockIdx.x * 256 + threadIdx.x;
    if (b < nbk) {
        int node = b << BKT_SHIFT;
        gcur[b] = row_start[node < n ? node : n];
    }
}

// group (pos,src) pairs by 512-node bucket; contiguous runs per block
__global__ __launch_bounds__(256) void bucket_pairs(const int* __restrict__ src,
                                                    const int* __restrict__ dst,
                                                    const int* __restrict__ rank,
                                                    const int* __restrict__ row_start,
                                                    int* __restrict__ gcur,
                                                    int2* __restrict__ bstore,
                                                    int e, int nbk) {
    __shared__ int hist[128], lbase[128], lcur[128];
    const int tid = threadIdx.x;
    const int base = blockIdx.x * 4096;
    for (int b = tid; b < nbk; b += 256) hist[b] = 0;
    __syncthreads();

    int myb[16], mypos[16], mys[16];
#pragma unroll
    for (int k = 0; k < 16; ++k) {
        int e0 = base + k * 256 + tid;
        if (e0 < e) {
            int d = dst[e0];
            int b = d >> BKT_SHIFT;
            myb[k] = b;
            mypos[k] = row_start[d] + 1 + rank[e0];
            mys[k] = src[e0];
            atomicAdd(&hist[b], 1);
        } else {
            myb[k] = -1;
        }
    }
    __syncthreads();
    for (int b = tid; b < nbk; b += 256) {
        int h = hist[b];
        lbase[b] = h ? atomicAdd(&gcur[b], h) : 0;
        lcur[b] = 0;
    }
    __syncthreads();
#pragma unroll
    for (int k = 0; k < 16; ++k) {
        if (myb[k] >= 0) {
            int off = atomicAdd(&lcur[myb[k]], 1);
            bstore[lbase[myb[k]] + off] = make_int2(mypos[k], mys[k]);
        }
    }
}

// one block per bucket: all writes land in this bucket's private adj window
__global__ __launch_bounds__(256) void scatter_local(const int* __restrict__ row_start,
                                                     const int* __restrict__ gcur,
                                                     const int2* __restrict__ bstore,
                                                     int* __restrict__ adj,
                                                     int n) {
    int b = blockIdx.x;
    int node = b << BKT_SHIFT;
    int lo = row_start[node < n ? node : n];
    int hi = gcur[b];
    for (int i = lo + threadIdx.x; i < hi; i += 256) {
        int2 p = bstore[i];
        adj[p.x] = p.y;
    }
}

// ---- GEMM 64x128 tile + fused attention dots, fp16 output -----------------
// h16[n,128] = fp16(A[n,K] @ B[K,128]); es2/ed2[row] = per-head <C_row, att>.
// thread (tx,ty): rows ty*4+r (r<4); cols tx*4+c (head0) and 64+tx*4+c (head1).
// A-tile stored transposed (Ast[k][row]) so inner loop is 3x ds_read_b128.

__global__ __launch_bounds__(256) void gemm64_dots(const float* __restrict__ A,
                                                   const float* __restrict__ B,
                                                   __half* __restrict__ h16,
                                                   const float* __restrict__ att_s,
                                                   const float* __restrict__ att_d,
                                                   float2* __restrict__ es2,
                                                   float2* __restrict__ ed2,
                                                   int nrows, int K) {
    __shared__ float Ast[32][68];    // [k][row], stride 68 keeps b128 alignment
    __shared__ float Bs[32][128];
    const int tid = threadIdx.x;
    const int tx = tid & 15;
    const int ty = tid >> 4;
    const int row0 = blockIdx.x * 64;

    float acc0[4][4], acc1[4][4];
#pragma unroll
    for (int r = 0; r < 4; ++r)
#pragma unroll
        for (int c = 0; c < 4; ++c) { acc0[r][c] = 0.f; acc1[r][c] = 0.f; }

    for (int k0 = 0; k0 < K; k0 += 32) {
        // A tile 64x32, stored transposed
#pragma unroll
        for (int i = 0; i < 2; ++i) {
            int idx = tid + i * 256;
            int r = idx >> 3;
            int c4 = (idx & 7) * 4;
            float4 v = make_float4(0.f, 0.f, 0.f, 0.f);
            int row = row0 + r;
            if (row < nrows) v = *(const float4*)(A + (size_t)row * K + k0 + c4);
            Ast[c4 + 0][r] = v.x; Ast[c4 + 1][r] = v.y;
            Ast[c4 + 2][r] = v.z; Ast[c4 + 3][r] = v.w;
        }
        // B tile 32x128
#pragma unroll
        for (int i = 0; i < 4; ++i) {
            int idx = tid + i * 256;
            int r = idx >> 5;
            int c4 = (idx & 31) * 4;
            float4 v = *(const float4*)(B + (size_t)(k0 + r) * FLATC + c4);
            *(float4*)&Bs[r][c4] = v;
        }
        __syncthreads();
#pragma unroll
        for (int kk = 0; kk < 32; ++kk) {
            float4 a  = *(const float4*)&Ast[kk][ty * 4];
            float4 b0 = *(const float4*)&Bs[kk][tx * 4];
            float4 b1 = *(const float4*)&Bs[kk][64 + tx * 4];
            const float ar[4] = {a.x, a.y, a.z, a.w};
            const float b0r[4] = {b0.x, b0.y, b0.z, b0.w};
            const float b1r[4] = {b1.x, b1.y, b1.z, b1.w};
#pragma unroll
            for (int r = 0; r < 4; ++r)
#pragma unroll
                for (int c = 0; c < 4; ++c) {
                    acc0[r][c] = fmaf(ar[r], b0r[c], acc0[r][c]);
                    acc1[r][c] = fmaf(ar[r], b1r[c], acc1[r][c]);
                }
        }
        __syncthreads();
    }

    // epilogue: h16 write + attention dots (16-lane shuffle reduce over tx)
    float as0[4], as1[4], ad0[4], ad1[4];
#pragma unroll
    for (int c = 0; c < 4; ++c) {
        as0[c] = att_s[tx * 4 + c];
        as1[c] = att_s[64 + tx * 4 + c];
        ad0[c] = att_d[tx * 4 + c];
        ad1[c] = att_d[64 + tx * 4 + c];
    }
#pragma unroll
    for (int r = 0; r < 4; ++r) {
        int row = row0 + ty * 4 + r;
        float s0 = 0.f, s1 = 0.f, d0 = 0.f, d1 = 0.f;
#pragma unroll
        for (int c = 0; c < 4; ++c) {
            s0 = fmaf(acc0[r][c], as0[c], s0);
            d0 = fmaf(acc0[r][c], ad0[c], d0);
            s1 = fmaf(acc1[r][c], as1[c], s1);
            d1 = fmaf(acc1[r][c], ad1[c], d1);
        }
#pragma unroll
        for (int m = 1; m < 16; m <<= 1) {
            s0 += __shfl_xor(s0, m);
            s1 += __shfl_xor(s1, m);
            d0 += __shfl_xor(d0, m);
            d1 += __shfl_xor(d1, m);
        }
        if (row < nrows) {
            __half* hp = h16 + (size_t)row * FLATC;
            *(__half2*)(hp + tx * 4)      = __floats2half2_rn(acc0[r][0], acc0[r][1]);
            *(__half2*)(hp + tx * 4 + 2)  = __floats2half2_rn(acc0[r][2], acc0[r][3]);
            *(__half2*)(hp + 64 + tx * 4) = __floats2half2_rn(acc1[r][0], acc1[r][1]);
            *(__half2*)(hp + 66 + tx * 4) = __floats2half2_rn(acc1[r][2], acc1[r][3]);
            if (tx == 0) {
                es2[row] = make_float2(s0, s1);
                ed2[row] = make_float2(d0, d1);
            }
        }
    }
}

// ---- softmax + per-edge alpha (wave per node) -----------------------------

__global__ __launch_bounds__(256) void softmax_alpha(const int* __restrict__ row_start,
                                                     const int* __restrict__ adj,
                                                     const float2* __restrict__ es2,
                                                     const float2* __restrict__ ed2,
                                                     float2* __restrict__ alpha2,
                                                     int n) {
    int node = blockIdx.x * 4 + (threadIdx.x >> 6);
    if (node >= n) return;
    const int lane = threadIdx.x & 63;
    const int beg = row_start[node];
    const int end = row_start[node + 1];
    const float2 edv = ed2[node];

    if (end - beg <= 64) {
        int j = beg + lane;
        bool act = j < end;
        int id = adj[act ? j : beg];
        float2 ev = es2[id];
        float f0 = lrelu02(ev.x + edv.x);
        float f1 = lrelu02(ev.y + edv.y);
        float m0 = act ? f0 : -3.0e38f;
        float m1 = act ? f1 : -3.0e38f;
#pragma unroll
        for (int off = 1; off < 64; off <<= 1) {
            m0 = fmaxf(m0, __shfl_xor(m0, off));
            m1 = fmaxf(m1, __shfl_xor(m1, off));
        }
        float p0 = act ? expf(f0 - m0) : 0.f;
        float p1 = act ? expf(f1 - m1) : 0.f;
        float s0 = p0, s1 = p1;
#pragma unroll
        for (int off = 1; off < 64; off <<= 1) {
            s0 += __shfl_xor(s0, off);
            s1 += __shfl_xor(s1, off);
        }
        if (act)
            alpha2[j] = make_float2(p0 / (s0 + 1e-16f), p1 / (s1 + 1e-16f));
        return;
    }

    // general path (deg > 64)
    float m0 = -3.0e38f, m1 = -3.0e38f;
    float s0 = 0.f, s1 = 0.f;
    for (int j = beg + lane; j < end; j += 64) {
        float2 ev = es2[adj[j]];
        float f0 = lrelu02(ev.x + edv.x);
        float f1 = lrelu02(ev.y + edv.y);
        float mn0 = fmaxf(m0, f0);
        s0 = s0 * expf(m0 - mn0) + expf(f0 - mn0);
        m0 = mn0;
        float mn1 = fmaxf(m1, f1);
        s1 = s1 * expf(m1 - mn1) + expf(f1 - mn1);
        m1 = mn1;
    }
#pragma unroll
    for (int off = 1; off < 64; off <<= 1) {
        float mo0 = __shfl_xor(m0, off), so0 = __shfl_xor(s0, off);
        float mo1 = __shfl_xor(m1, off), so1 = __shfl_xor(s1, off);
        float mn0 = fmaxf(m0, mo0);
        s0 = s0 * expf(m0 - mn0) + so0 * expf(mo0 - mn0);
        m0 = mn0;
        float mn1 = fmaxf(m1, mo1);
        s1 = s1 * expf(m1 - mn1) + so1 * expf(mo1 - mn1);
        m1 = mn1;
    }
    const float inv0 = 1.f / (s0 + 1e-16f);
    const float inv1 = 1.f / (s1 + 1e-16f);
    for (int j = beg + lane; j < end; j += 64) {
        float2 ev = es2[adj[j]];
        float f0 = lrelu02(ev.x + edv.x);
        float f1 = lrelu02(ev.y + edv.y);
        alpha2[j] = make_float2(expf(f0 - m0) * inv0, expf(f1 - m1) * inv1);
    }
}

// ---- aggregate: out[n,64] = mean_h(sum_j alpha_j * h16[adj_j]) + bias -----

__global__ __launch_bounds__(256) void agg(const int* __restrict__ row_start,
                                           const int* __restrict__ adj,
                                           const __half2* __restrict__ h16,
                                           const float2* __restrict__ alpha2,
                                           const float* __restrict__ bias,
                                           float* __restrict__ out,
                                           int n, int do_relu) {
    int node = blockIdx.x * 4 + (threadIdx.x >> 6);
    if (node >= n) return;
    const int lane = threadIdx.x & 63;
    const int head = lane >> 5;
    const int beg = row_start[node];
    const int end = row_start[node + 1];
    const __half2* hp = h16 + lane;      // h16 row = 64 __half2

    float ax = 0.f, ay = 0.f;
    int j = beg;
    for (; j + 4 <= end; j += 4) {
        int i0 = adj[j], i1 = adj[j + 1], i2 = adj[j + 2], i3 = adj[j + 3];
        float2 a0 = alpha2[j], a1 = alpha2[j + 1];
        float2 a2 = alpha2[j + 2], a3 = alpha2[j + 3];
        __half2 v0 = hp[(size_t)i0 * 64];
        __half2 v1 = hp[(size_t)i1 * 64];
        __half2 v2 = hp[(size_t)i2 * 64];
        __half2 v3 = hp[(size_t)i3 * 64];
        float w0 = head ? a0.y : a0.x;
        float w1 = head ? a1.y : a1.x;
        float w2 = head ? a2.y : a2.x;
        float w3 = head ? a3.y : a3.x;
        float2 f0 = __half22float2(v0);
        float2 f1 = __half22float2(v1);
        float2 f2 = __half22float2(v2);
        float2 f3 = __half22float2(v3);
        ax = fmaf(w0, f0.x, ax); ay = fmaf(w0, f0.y, ay);
        ax = fmaf(w1, f1.x, ax); ay = fmaf(w1, f1.y, ay);
        ax = fmaf(w2, f2.x, ax); ay = fmaf(w2, f2.y, ay);
        ax = fmaf(w3, f3.x, ax); ay = fmaf(w3, f3.y, ay);
    }
    for (; j < end; ++j) {
        int i0 = adj[j];
        float2 a0 = alpha2[j];
        float w0 = head ? a0.y : a0.x;
        float2 f0 = __half22float2(hp[(size_t)i0 * 64]);
        ax = fmaf(w0, f0.x, ax); ay = fmaf(w0, f0.y, ay);
    }

    float ox = 0.5f * (ax + __shfl_xor(ax, 32));
    float oy = 0.5f * (ay + __shfl_xor(ay, 32));
    if (lane < 32) {
        int c = 2 * lane;
        ox += bias[c];
        oy += bias[c + 1];
        if (do_relu) { ox = fmaxf(ox, 0.f); oy = fmaxf(oy, 0.f); }
        *(float2*)(out + (size_t)node * 64 + c) = make_float2(ox, oy);
    }
}

// ---------------------------------------------------------------------------

extern "C" void kernel_launch(void* const* d_in, const int* in_sizes, int n_in,
                              void* d_out, int out_size, void* d_ws, size_t ws_size,
                              hipStream_t stream) {
    const float* x   = (const float*)d_in[0];
    const int*   ei  = (const int*)d_in[1];
    const float* W1  = (const float*)d_in[2];
    const float* as1 = (const float*)d_in[3];
    const float* ad1 = (const float*)d_in[4];
    const float* b1  = (const float*)d_in[5];
    const float* W2  = (const float*)d_in[6];
    const float* as2 = (const float*)d_in[7];
    const float* ad2 = (const float*)d_in[8];
    const float* b2  = (const float*)d_in[9];

    const int N_ = in_sizes[0] / IN_DIM;   // 50000
    const int E_ = in_sizes[1] / 2;        // 800000
    const int* src = ei;
    const int* dst = ei + E_;
    const int TOT = E_ + N_;               // CSR slots incl self loops
    const int NBK = (N_ + (1 << BKT_SHIFT) - 1) >> BKT_SHIFT;   // 98

    auto align16 = [](size_t v) { return (v + 15) & ~(size_t)15; };
    char* p = (char*)d_ws;
    int* cnt       = (int*)p; p += align16((size_t)N_ * 4);
    int* row_start = (int*)p; p += align16((size_t)(N_ + 1) * 4);
    int* rank      = (int*)p; p += align16((size_t)E_ * 4);
    int* adj       = (int*)p; p += align16((size_t)TOT * 4);
    int* bsum      = (int*)p; p += align16((size_t)1024 * 4);
    int* boff      = (int*)p; p += align16((size_t)1024 * 4);
    int* gcur      = (int*)p; p += align16((size_t)128 * 4);
    int2* bstore   = (int2*)p; p += align16((size_t)TOT * 8);
    __half* h16    = (__half*)p; p += align16((size_t)N_ * FLATC * 2);
    float* out1    = (float*)p; p += align16((size_t)N_ * 64 * 4);
    float* es      = (float*)p; p += align16((size_t)N_ * 2 * 4);
    float* ed      = (float*)p; p += align16((size_t)N_ * 2 * 4);
    float* alpha   = (float*)p; p += align16((size_t)TOT * 2 * 4);
    (void)ws_size; (void)n_in; (void)out_size;

    const int NB = (N_ + 255) / 256;

    // --- CSR build (self-loops at slot 0; bucketed XCD-local scatter) ---
    hipMemsetAsync(cnt, 0, (size_t)N_ * 4, stream);
    count_kernel<<<(E_ + 255) / 256, 256, 0, stream>>>(dst, cnt, rank, E_);
    scan_bsum<<<NB, 256, 0, stream>>>(cnt, bsum, N_);
    scan_boff<<<1, 1024, 0, stream>>>(bsum, boff, row_start, NB, N_);
    scan_write<<<NB, 256, 0, stream>>>(cnt, boff, row_start, adj, N_);
    init_gcur<<<1, 256, 0, stream>>>(row_start, gcur, NBK, N_);
    bucket_pairs<<<(E_ + 4095) / 4096, 256, 0, stream>>>(src, dst, rank, row_start,
                                                         gcur, bstore, E_, NBK);
    scatter_local<<<NBK, 256, 0, stream>>>(row_start, gcur, bstore, adj, N_);

    const int gG = (N_ + 63) / 64;
    const int gN4 = (N_ + 3) / 4;

    // --- layer 1 ---
    gemm64_dots<<<gG, 256, 0, stream>>>(x, W1, h16, as1, ad1,
                                        (float2*)es, (float2*)ed, N_, IN_DIM);
    softmax_alpha<<<gN4, 256, 0, stream>>>(row_start, adj, (const float2*)es,
                                           (const float2*)ed, (float2*)alpha, N_);
    agg<<<gN4, 256, 0, stream>>>(row_start, adj, (const __half2*)h16,
                                 (const float2*)alpha, b1, out1, N_, 1);

    // --- layer 2 ---
    gemm64_dots<<<gG, 256, 0, stream>>>(out1, W2, h16, as2, ad2,
                                        (float2*)es, (float2*)ed, N_, 64);
    softmax_alpha<<<gN4, 256, 0, stream>>>(row_start, adj, (const float2*)es,
                                           (const float2*)ed, (float2*)alpha, N_);
    agg<<<gN4, 256, 0, stream>>>(row_start, adj, (const __half2*)h16,
                                 (const float2*)alpha, b2, (float*)d_out, N_, 0);
}